// Round 1
// baseline (1567.635 us; speedup 1.0000x reference)
//
#include <hip/hip_runtime.h>
#include <math.h>

#define NL 4
#define DMODEL 768
#define DINNER 1536
#define DSTATE 16
#define DCONV 4
#define DTRANK 48
#define BATCH 2
#define SEQLEN 1024
#define MTOK (BATCH*SEQLEN)      // 2048
#define XDIM 80                  // DTRANK + 2*DSTATE
#define NCHUNK 32
#define CLEN 32                  // SEQLEN/NCHUNK
#define CHSTRIDE (BATCH*16*DINNER)   // 49152

typedef __bf16 bf16x8 __attribute__((ext_vector_type(8)));
typedef float f32x4 __attribute__((ext_vector_type(4)));

__device__ __forceinline__ void splitbf(float f, unsigned short& hi, unsigned short& lo) {
    unsigned uh = __float_as_uint(f);
    unsigned rh = uh + (0x7fffu + ((uh >> 16) & 1u));
    unsigned short h = (unsigned short)(rh >> 16);
    float fh = __uint_as_float(((unsigned)h) << 16);
    float r = f - fh;
    unsigned ul = __float_as_uint(r);
    unsigned rl = ul + (0x7fffu + ((ul >> 16) & 1u));
    hi = h;
    lo = (unsigned short)(rl >> 16);
}

// ---------------------------------------------------------------------------
// Split-bf16 (3-pass) MFMA GEMM: C[M,N] = A[M,K] @ W[N,K]^T, all fp32 in/out.
// Block = 256 threads = 4 waves (2x2), wave tile (BM/2)x(BN/2) of 16x16 MFMAs.
// ---------------------------------------------------------------------------
template<int BM, int BN>
__global__ __launch_bounds__(256, 2) void gemm_bf16x3(
    const float* __restrict__ A, int lda,
    const float* __restrict__ W, int ldw,
    float* __restrict__ C, int ldc, int K)
{
    constexpr int MT = BM / 32;
    constexpr int NT = BN / 32;
    __shared__ unsigned short As[2][BM][40];   // [hi/lo][row][k], pad to 40 (80B rows, 16B aligned)
    __shared__ unsigned short Ws[2][BN][40];

    const int tid = threadIdx.x;
    const int m0 = blockIdx.y * BM, n0 = blockIdx.x * BN;
    const int wave = tid >> 6, lane = tid & 63;
    const int wr = wave >> 1, wc = wave & 1;
    const int wm0 = wr * (BM / 2), wn0 = wc * (BN / 2);
    const int lrow = lane & 15, lq = lane >> 4;

    f32x4 acc[MT][NT];
    #pragma unroll
    for (int mt = 0; mt < MT; mt++)
        #pragma unroll
        for (int nt = 0; nt < NT; nt++) {
            f32x4 z = {0.f, 0.f, 0.f, 0.f};
            acc[mt][nt] = z;
        }

    for (int k0 = 0; k0 < K; k0 += 32) {
        // stage A tile (BM x 32 floats) with on-the-fly hi/lo split
        #pragma unroll
        for (int idx = tid * 4; idx < BM * 32; idx += 1024) {
            int rr = idx >> 5, cc = idx & 31;
            float4 v = *(const float4*)(A + (size_t)(m0 + rr) * lda + k0 + cc);
            ushort4 h4, l4;
            splitbf(v.x, h4.x, l4.x);
            splitbf(v.y, h4.y, l4.y);
            splitbf(v.z, h4.z, l4.z);
            splitbf(v.w, h4.w, l4.w);
            *(ushort4*)&As[0][rr][cc] = h4;
            *(ushort4*)&As[1][rr][cc] = l4;
        }
        #pragma unroll
        for (int idx = tid * 4; idx < BN * 32; idx += 1024) {
            int rr = idx >> 5, cc = idx & 31;
            float4 v = *(const float4*)(W + (size_t)(n0 + rr) * ldw + k0 + cc);
            ushort4 h4, l4;
            splitbf(v.x, h4.x, l4.x);
            splitbf(v.y, h4.y, l4.y);
            splitbf(v.z, h4.z, l4.z);
            splitbf(v.w, h4.w, l4.w);
            *(ushort4*)&Ws[0][rr][cc] = h4;
            *(ushort4*)&Ws[1][rr][cc] = l4;
        }
        __syncthreads();

        bf16x8 ah[MT], al[MT], wh[NT], wl[NT];
        #pragma unroll
        for (int mt = 0; mt < MT; mt++) {
            int rrow = wm0 + mt * 16 + lrow;
            ah[mt] = *(const bf16x8*)&As[0][rrow][lq * 8];
            al[mt] = *(const bf16x8*)&As[1][rrow][lq * 8];
        }
        #pragma unroll
        for (int nt = 0; nt < NT; nt++) {
            int rrow = wn0 + nt * 16 + lrow;
            wh[nt] = *(const bf16x8*)&Ws[0][rrow][lq * 8];
            wl[nt] = *(const bf16x8*)&Ws[1][rrow][lq * 8];
        }
        #pragma unroll
        for (int mt = 0; mt < MT; mt++)
            #pragma unroll
            for (int nt = 0; nt < NT; nt++) {
                acc[mt][nt] = __builtin_amdgcn_mfma_f32_16x16x32_bf16(ah[mt], wh[nt], acc[mt][nt], 0, 0, 0);
                acc[mt][nt] = __builtin_amdgcn_mfma_f32_16x16x32_bf16(ah[mt], wl[nt], acc[mt][nt], 0, 0, 0);
                acc[mt][nt] = __builtin_amdgcn_mfma_f32_16x16x32_bf16(al[mt], wh[nt], acc[mt][nt], 0, 0, 0);
            }
        __syncthreads();
    }

    // C/D layout: col = lane&15, row = (lane>>4)*4 + reg   [measured m89/m91]
    #pragma unroll
    for (int mt = 0; mt < MT; mt++)
        #pragma unroll
        for (int nt = 0; nt < NT; nt++)
            #pragma unroll
            for (int i = 0; i < 4; i++) {
                int row = m0 + wm0 + mt * 16 + lq * 4 + i;
                int col = n0 + wn0 + nt * 16 + lrow;
                C[(size_t)row * ldc + col] = acc[mt][nt][i];
            }
}

// ---------------------------------------------------------------------------
// fp32 tiled GEMM (small GEMMs). C = A[M,K] @ W[N,K]^T.
// EPI: 1 = atomicAdd (split-K), 2 = softplus(acc + bias[n])
// ---------------------------------------------------------------------------
template<int BM, int BN, int BK, int TM, int TN, int EPI>
__global__ __launch_bounds__(256, 4) void gemm_f32(
    const float* __restrict__ A, int lda,
    const float* __restrict__ W, int ldw,
    float* __restrict__ C, int ldc,
    int kLen, const float* __restrict__ bias)
{
    static_assert(BK == 16, "staging assumes BK==16");
    __shared__ float As[BK][BM + 4];
    __shared__ float Ws[BK][BN + 4];
    const int tid = threadIdx.x;
    const int tx = tid & 15, ty = tid >> 4;
    const int m0 = blockIdx.y * BM, n0 = blockIdx.x * BN;
    const int k0 = blockIdx.z * kLen;

    float acc[TM][TN];
    #pragma unroll
    for (int i = 0; i < TM; i++)
        #pragma unroll
        for (int j = 0; j < TN; j++) acc[i][j] = 0.f;

    for (int kk = k0; kk < k0 + kLen; kk += BK) {
        for (int idx = tid; idx < BM * BK; idx += 256) {
            int rr = idx >> 4, cc = idx & 15;
            As[cc][rr] = A[(size_t)(m0 + rr) * lda + kk + cc];
        }
        for (int idx = tid; idx < BN * BK; idx += 256) {
            int rr = idx >> 4, cc = idx & 15;
            Ws[cc][rr] = W[(size_t)(n0 + rr) * ldw + kk + cc];
        }
        __syncthreads();
        #pragma unroll
        for (int k = 0; k < BK; k++) {
            float a[TM], b[TN];
            #pragma unroll
            for (int i = 0; i < TM; i++) a[i] = As[k][ty * TM + i];
            #pragma unroll
            for (int j = 0; j < TN; j++) b[j] = Ws[k][tx * TN + j];
            #pragma unroll
            for (int i = 0; i < TM; i++)
                #pragma unroll
                for (int j = 0; j < TN; j++) acc[i][j] = fmaf(a[i], b[j], acc[i][j]);
        }
        __syncthreads();
    }

    #pragma unroll
    for (int i = 0; i < TM; i++) {
        int row = m0 + ty * TM + i;
        #pragma unroll
        for (int j = 0; j < TN; j++) {
            int col = n0 + tx * TN + j;
            if (EPI == 1) {
                atomicAdd(&C[(size_t)row * ldc + col], acc[i][j]);
            } else if (EPI == 2) {
                float v = acc[i][j] + bias[col];
                // softplus = max(v,0) + log1p(exp(-|v|))
                C[(size_t)row * ldc + col] = fmaxf(v, 0.f) + log1pf(__expf(-fabsf(v)));
            } else {
                C[(size_t)row * ldc + col] = acc[i][j];
            }
        }
    }
}

// ---------------------------------------------------------------------------
// causal depthwise conv (width 4) + silu:  u[b,l,d] = silu(sum_j cw[d,j]*ur[b,l-3+j,d] + cb[d])
// ur = first half of xz rows ([MTOK, 2*DINNER])
// ---------------------------------------------------------------------------
__global__ __launch_bounds__(256) void conv_silu_kernel(
    const float* __restrict__ xz, const float* __restrict__ cw,
    const float* __restrict__ cb, float* __restrict__ u)
{
    int idx = blockIdx.x * 256 + threadIdx.x;   // over MTOK*DINNER
    int d = idx % DINNER;
    int r = idx / DINNER;          // b*SEQLEN + l
    int l = r & (SEQLEN - 1);
    const float* base = xz + (size_t)r * (2 * DINNER) + d;
    float acc = cb[d];
    float w0 = cw[d * 4 + 0], w1 = cw[d * 4 + 1], w2 = cw[d * 4 + 2], w3 = cw[d * 4 + 3];
    if (l >= 3) acc = fmaf(w0, base[-3 * 2 * DINNER], acc);
    if (l >= 2) acc = fmaf(w1, base[-2 * 2 * DINNER], acc);
    if (l >= 1) acc = fmaf(w2, base[-1 * 2 * DINNER], acc);
    acc = fmaf(w3, base[0], acc);
    u[idx] = acc / (1.f + __expf(-acc));
}

// ---------------------------------------------------------------------------
// Chunked parallel scan. h_t = dA_t*h_{t-1} + dBu_t (diagonal linear recurrence)
// pass1: per-(b,d,chunk) compute P = prod(dA), q = state with h0=0
// pass2: per-(b,n,d) sequential over 32 chunks -> hinit per chunk
// pass3: per-(b,d,chunk) recompute with known hinit, emit gated y
// buffers laid out [chunk][b][n][d] for coalescing in all passes
// ---------------------------------------------------------------------------
__global__ __launch_bounds__(256, 4) void scan_pass1(
    const float* __restrict__ delta, const float* __restrict__ u,
    const float* __restrict__ xdbl, const float* __restrict__ A_log,
    float* __restrict__ pbuf, float* __restrict__ qbuf)
{
    int gid = blockIdx.x * 256 + threadIdx.x;  // BATCH*NCHUNK*DINNER
    int d = gid % DINNER;
    int r = gid / DINNER;
    int chunk = r & (NCHUNK - 1);
    int b = r >> 5;
    float Arow[16], p[16], q[16];
    #pragma unroll
    for (int n = 0; n < 16; n++) {
        Arow[n] = -__expf(A_log[d * 16 + n]);
        p[n] = 1.f;
        q[n] = 0.f;
    }
    const float* drow = delta + (size_t)b * SEQLEN * DINNER + d;
    const float* urow = u + (size_t)b * SEQLEN * DINNER + d;
    int t0 = chunk * CLEN;
    for (int i = 0; i < CLEN; i++) {
        int t = t0 + i;
        float dl = drow[(size_t)t * DINNER];
        float uu = urow[(size_t)t * DINNER];
        float du = dl * uu;
        const float* Bp = xdbl + (size_t)(b * SEQLEN + t) * XDIM + DTRANK;
        #pragma unroll
        for (int n = 0; n < 16; n++) {
            float dA = __expf(dl * Arow[n]);
            q[n] = fmaf(dA, q[n], du * Bp[n]);
            p[n] *= dA;
        }
    }
    size_t off = (size_t)((chunk * BATCH + b) * 16) * DINNER + d;
    #pragma unroll
    for (int n = 0; n < 16; n++) {
        pbuf[off + (size_t)n * DINNER] = p[n];
        qbuf[off + (size_t)n * DINNER] = q[n];
    }
}

__global__ __launch_bounds__(256) void scan_pass2(
    const float* __restrict__ pbuf, const float* __restrict__ qbuf,
    float* __restrict__ hinit)
{
    int gid = blockIdx.x * 256 + threadIdx.x;   // BATCH*16*DINNER
    float h = 0.f;
    for (int c = 0; c < NCHUNK; c++) {
        size_t o = (size_t)c * CHSTRIDE + gid;
        hinit[o] = h;
        h = fmaf(pbuf[o], h, qbuf[o]);
    }
}

__global__ __launch_bounds__(256, 4) void scan_pass3(
    const float* __restrict__ delta, const float* __restrict__ u,
    const float* __restrict__ xdbl, const float* __restrict__ xz,
    const float* __restrict__ A_log, const float* __restrict__ Dp,
    const float* __restrict__ hinit, float* __restrict__ y)
{
    int gid = blockIdx.x * 256 + threadIdx.x;
    int d = gid % DINNER;
    int r = gid / DINNER;
    int chunk = r & (NCHUNK - 1);
    int b = r >> 5;
    float Arow[16], h[16];
    #pragma unroll
    for (int n = 0; n < 16; n++) Arow[n] = -__expf(A_log[d * 16 + n]);
    size_t hoff = (size_t)chunk * CHSTRIDE + (size_t)(b * 16) * DINNER + d;
    #pragma unroll
    for (int n = 0; n < 16; n++) h[n] = hinit[hoff + (size_t)n * DINNER];
    float Dpar = Dp[d];
    const float* drow = delta + (size_t)b * SEQLEN * DINNER + d;
    const float* urow = u + (size_t)b * SEQLEN * DINNER + d;
    int t0 = chunk * CLEN;
    for (int i = 0; i < CLEN; i++) {
        int t = t0 + i;
        float dl = drow[(size_t)t * DINNER];
        float uu = urow[(size_t)t * DINNER];
        float du = dl * uu;
        const float* Bp = xdbl + (size_t)(b * SEQLEN + t) * XDIM + DTRANK;
        float yt = 0.f;
        #pragma unroll
        for (int n = 0; n < 16; n++) {
            float dA = __expf(dl * Arow[n]);
            h[n] = fmaf(dA, h[n], du * Bp[n]);
            yt = fmaf(h[n], Bp[16 + n], yt);
        }
        yt = fmaf(uu, Dpar, yt);
        float z = xz[(size_t)(b * SEQLEN + t) * (2 * DINNER) + DINNER + d];
        float sz = z / (1.f + __expf(-z));
        y[(size_t)(b * SEQLEN + t) * DINNER + d] = yt * sz;
    }
}

// ---------------------------------------------------------------------------
extern "C" void kernel_launch(void* const* d_in, const int* in_sizes, int n_in,
                              void* d_out, int out_size, void* d_ws, size_t ws_size,
                              hipStream_t stream) {
    const float* x    = (const float*)d_in[0];
    const float* ipw  = (const float*)d_in[1];
    const float* cw   = (const float*)d_in[2];
    const float* cb   = (const float*)d_in[3];
    const float* xpw  = (const float*)d_in[4];
    const float* dpw  = (const float*)d_in[5];
    const float* dpb  = (const float*)d_in[6];
    const float* alog = (const float*)d_in[7];
    const float* dpar = (const float*)d_in[8];
    const float* opw  = (const float*)d_in[9];
    float* out = (float*)d_out;

    float* ws = (float*)d_ws;
    float* xz    = ws;                      // 2048*3072   = 6291456
    float* u     = xz    + 6291456;         // 2048*1536   = 3145728
    float* xdbl  = u     + 3145728;         // 2048*80     = 163840
    float* delta = xdbl  + 163840;          // 3145728
    float* ybuf  = delta + 3145728;         // 3145728
    float* pbuf  = ybuf  + 3145728;         // 32*49152    = 1572864
    float* qbuf  = pbuf  + 1572864;         // 1572864
    float* hinit = qbuf  + 1572864;         // 1572864
    float* xb0   = hinit + 1572864;         // 1572864
    float* xb1   = xb0   + 1572864;         // 1572864

    const float* cur = x;
    for (int L = 0; L < NL; L++) {
        const float* ipw_l  = ipw  + (size_t)L * 2 * DINNER * DMODEL;
        const float* cw_l   = cw   + (size_t)L * DINNER * DCONV;
        const float* cb_l   = cb   + (size_t)L * DINNER;
        const float* xpw_l  = xpw  + (size_t)L * XDIM * DINNER;
        const float* dpw_l  = dpw  + (size_t)L * DINNER * DTRANK;
        const float* dpb_l  = dpb  + (size_t)L * DINNER;
        const float* alog_l = alog + (size_t)L * DINNER * DSTATE;
        const float* dpar_l = dpar + (size_t)L * DINNER;
        const float* opw_l  = opw  + (size_t)L * DMODEL * DINNER;
        float* dst = (L == NL - 1) ? out : ((L & 1) ? xb1 : xb0);

        // GEMM1: xz[2048,3072] = cur[2048,768] @ ipw^T
        gemm_bf16x3<128, 128><<<dim3(3072 / 128, 2048 / 128), 256, 0, stream>>>(
            cur, DMODEL, ipw_l, DMODEL, xz, 2 * DINNER, DMODEL);

        // conv + silu -> u
        conv_silu_kernel<<<(MTOK * DINNER) / 256, 256, 0, stream>>>(xz, cw_l, cb_l, u);

        // GEMM2 (split-K, atomic): xdbl[2048,80] = u @ xpw^T
        hipMemsetAsync(xdbl, 0, (size_t)MTOK * XDIM * sizeof(float), stream);
        gemm_f32<64, 80, 16, 4, 5, 1><<<dim3(1, 2048 / 64, 8), 256, 0, stream>>>(
            u, DINNER, xpw_l, DINNER, xdbl, XDIM, DINNER / 8, nullptr);

        // GEMM3: delta = softplus(xdbl[:, :48] @ dpw^T + dpb)
        gemm_f32<64, 64, 16, 4, 4, 2><<<dim3(1536 / 64, 2048 / 64, 1), 256, 0, stream>>>(
            xdbl, XDIM, dpw_l, DTRANK, delta, DINNER, DTRANK, dpb_l);

        // chunked scan
        scan_pass1<<<(BATCH * NCHUNK * DINNER) / 256, 256, 0, stream>>>(
            delta, u, xdbl, alog_l, pbuf, qbuf);
        scan_pass2<<<CHSTRIDE / 256, 256, 0, stream>>>(pbuf, qbuf, hinit);
        scan_pass3<<<(BATCH * NCHUNK * DINNER) / 256, 256, 0, stream>>>(
            delta, u, xdbl, xz, alog_l, dpar_l, hinit, ybuf);

        // GEMM4: dst[2048,768] = ybuf[2048,1536] @ opw^T
        gemm_bf16x3<64, 64><<<dim3(768 / 64, 2048 / 64), 256, 0, stream>>>(
            ybuf, DINNER, opw_l, DINNER, dst, DMODEL, DINNER);

        cur = dst;
    }
    (void)in_sizes; (void)n_in; (void)out_size; (void)ws_size;
}

// Round 2
// 1130.749 us; speedup vs baseline: 1.3864x; 1.3864x over previous
//
#include <hip/hip_runtime.h>
#include <math.h>

#define NL 4
#define DMODEL 768
#define DINNER 1536
#define DSTATE 16
#define DCONV 4
#define DTRANK 48
#define BATCH 2
#define SEQLEN 1024
#define MTOK (BATCH*SEQLEN)      // 2048
#define XDIM 80                  // DTRANK + 2*DSTATE
#define NCHUNK 32
#define CLEN 32                  // SEQLEN/NCHUNK
#define CHSTRIDE (BATCH*16*DINNER)   // 49152

typedef __bf16 bf16x8 __attribute__((ext_vector_type(8)));
typedef float f32x4 __attribute__((ext_vector_type(4)));

__device__ __forceinline__ void splitbf(float f, unsigned short& hi, unsigned short& lo) {
    unsigned uh = __float_as_uint(f);
    unsigned rh = uh + (0x7fffu + ((uh >> 16) & 1u));
    unsigned short h = (unsigned short)(rh >> 16);
    float fh = __uint_as_float(((unsigned)h) << 16);
    float r = f - fh;
    unsigned ul = __float_as_uint(r);
    unsigned rl = ul + (0x7fffu + ((ul >> 16) & 1u));
    hi = h;
    lo = (unsigned short)(rl >> 16);
}

__device__ __forceinline__ void gload_lds16(const void* g, void* l) {
    __builtin_amdgcn_global_load_lds(
        (const __attribute__((address_space(1))) unsigned*)g,
        (__attribute__((address_space(3))) unsigned*)l, 16, 0, 0);
}

// ---------------------------------------------------------------------------
// elementwise fp32 -> (bf16 hi, bf16 lo) split, float4 vectorized
// ---------------------------------------------------------------------------
__global__ __launch_bounds__(256) void split_kernel(
    const float* __restrict__ in, unsigned short* __restrict__ hi,
    unsigned short* __restrict__ lo, int n4)
{
    int i = blockIdx.x * 256 + threadIdx.x;
    if (i >= n4) return;
    float4 v = ((const float4*)in)[i];
    ushort4 h, l;
    splitbf(v.x, h.x, l.x);
    splitbf(v.y, h.y, l.y);
    splitbf(v.z, h.z, l.z);
    splitbf(v.w, h.w, l.w);
    ((ushort4*)hi)[i] = h;
    ((ushort4*)lo)[i] = l;
}

// ---------------------------------------------------------------------------
// Pre-split 3-pass bf16 MFMA GEMM (m97 structure):
// C[M,N] = (Ah+Al)[M,K] @ (Wh+Wl)[N,K]^T  (dropping Al*Wl)
// 128x128 block tile, BK=32, 4 waves (2x2), global_load_lds width=16 staging.
// blockIdx.z = split-K slice (k range [z*Klen, (z+1)*Klen)), C += z*zstride.
// ---------------------------------------------------------------------------
template<int BM, int BN>
__global__ __launch_bounds__(256, 2) void gemm_pre(
    const unsigned short* __restrict__ Ah, const unsigned short* __restrict__ Al, int lda,
    const unsigned short* __restrict__ Wh, const unsigned short* __restrict__ Wl, int ldw,
    float* __restrict__ C, int ldc, int Klen, size_t zstride)
{
    constexpr int BK = 32;
    constexpr int MT = BM / 32, NT = BN / 32;
    constexpr int AISS = BM * 4 / 256;   // 16B chunks per thread for an A tile
    constexpr int WISS = BN * 4 / 256;
    __shared__ unsigned short sAh[BM * BK];
    __shared__ unsigned short sAl[BM * BK];
    __shared__ unsigned short sWh[BN * BK];
    __shared__ unsigned short sWl[BN * BK];

    const int tid = threadIdx.x;
    const int m0 = blockIdx.y * BM, n0 = blockIdx.x * BN;
    const int kbase = blockIdx.z * Klen;
    C += (size_t)blockIdx.z * zstride;
    const int lane = tid & 63, wave = tid >> 6;
    const int wr = wave >> 1, wc = wave & 1;
    const int wm0 = wr * (BM / 2), wn0 = wc * (BN / 2);
    const int lrow = lane & 15, lq = lane >> 4;

    f32x4 acc[MT][NT];
    #pragma unroll
    for (int mt = 0; mt < MT; mt++)
        #pragma unroll
        for (int nt = 0; nt < NT; nt++) {
            f32x4 z = {0.f, 0.f, 0.f, 0.f};
            acc[mt][nt] = z;
        }

    for (int k0 = kbase; k0 < kbase + Klen; k0 += BK) {
        // stage tiles: row-major [rows][32 bf16], 4x 16B chunks per row;
        // lane-linear chunk order == LDS layout (global_load_lds constraint)
        #pragma unroll
        for (int i = 0; i < AISS; i++) {
            int chunk = i * 256 + tid;
            int r = chunk >> 2, c = (chunk & 3) * 8;
            size_t goff = (size_t)(m0 + r) * lda + k0 + c;
            gload_lds16(Ah + goff, &sAh[chunk * 8]);
            gload_lds16(Al + goff, &sAl[chunk * 8]);
        }
        #pragma unroll
        for (int i = 0; i < WISS; i++) {
            int chunk = i * 256 + tid;
            int r = chunk >> 2, c = (chunk & 3) * 8;
            size_t goff = (size_t)(n0 + r) * ldw + k0 + c;
            gload_lds16(Wh + goff, &sWh[chunk * 8]);
            gload_lds16(Wl + goff, &sWl[chunk * 8]);
        }
        __syncthreads();

        bf16x8 fah[MT], fal[MT], fwh[NT], fwl[NT];
        #pragma unroll
        for (int mt = 0; mt < MT; mt++) {
            int off = (wm0 + mt * 16 + lrow) * BK + lq * 8;
            fah[mt] = *(const bf16x8*)&sAh[off];
            fal[mt] = *(const bf16x8*)&sAl[off];
        }
        #pragma unroll
        for (int nt = 0; nt < NT; nt++) {
            int off = (wn0 + nt * 16 + lrow) * BK + lq * 8;
            fwh[nt] = *(const bf16x8*)&sWh[off];
            fwl[nt] = *(const bf16x8*)&sWl[off];
        }
        #pragma unroll
        for (int mt = 0; mt < MT; mt++)
            #pragma unroll
            for (int nt = 0; nt < NT; nt++) {
                acc[mt][nt] = __builtin_amdgcn_mfma_f32_16x16x32_bf16(fah[mt], fwh[nt], acc[mt][nt], 0, 0, 0);
                acc[mt][nt] = __builtin_amdgcn_mfma_f32_16x16x32_bf16(fah[mt], fwl[nt], acc[mt][nt], 0, 0, 0);
                acc[mt][nt] = __builtin_amdgcn_mfma_f32_16x16x32_bf16(fal[mt], fwh[nt], acc[mt][nt], 0, 0, 0);
            }
        __syncthreads();
    }

    // C/D layout: col = lane&15, row = (lane>>4)*4 + reg   [measured m89/m91]
    #pragma unroll
    for (int mt = 0; mt < MT; mt++)
        #pragma unroll
        for (int nt = 0; nt < NT; nt++)
            #pragma unroll
            for (int i = 0; i < 4; i++) {
                int row = m0 + wm0 + mt * 16 + lq * 4 + i;
                int col = n0 + wn0 + nt * 16 + lrow;
                C[(size_t)row * ldc + col] = acc[mt][nt][i];
            }
}

// ---------------------------------------------------------------------------
// split-K reduce (4 slices) + optional bf16 hi/lo split for next-layer A
// MODE 0: write fp32 only; MODE 1: write hi/lo only
// ---------------------------------------------------------------------------
template<int MODE>
__global__ __launch_bounds__(256) void reduce4(
    const float* __restrict__ part, float* __restrict__ dst,
    unsigned short* __restrict__ hi, unsigned short* __restrict__ lo)
{
    constexpr size_t S = (size_t)MTOK * DMODEL / 4;
    int i = blockIdx.x * 256 + threadIdx.x;
    const float4* p = (const float4*)part;
    float4 a = p[i], b = p[i + S], c = p[i + 2 * S], d = p[i + 3 * S];
    float4 s = {a.x + b.x + c.x + d.x, a.y + b.y + c.y + d.y,
                a.z + b.z + c.z + d.z, a.w + b.w + c.w + d.w};
    if (MODE == 0) {
        ((float4*)dst)[i] = s;
    } else {
        ushort4 h, l;
        splitbf(s.x, h.x, l.x);
        splitbf(s.y, h.y, l.y);
        splitbf(s.z, h.z, l.z);
        splitbf(s.w, h.w, l.w);
        ((ushort4*)hi)[i] = h;
        ((ushort4*)lo)[i] = l;
    }
}

// ---------------------------------------------------------------------------
// fp32 tiled GEMM (small GEMMs). C = A[M,K] @ W[N,K]^T.
// EPI: 1 = atomicAdd (split-K), 2 = softplus(acc + bias[n])
// ---------------------------------------------------------------------------
template<int BM, int BN, int BK, int TM, int TN, int EPI>
__global__ __launch_bounds__(256, 4) void gemm_f32(
    const float* __restrict__ A, int lda,
    const float* __restrict__ W, int ldw,
    float* __restrict__ C, int ldc,
    int kLen, const float* __restrict__ bias)
{
    static_assert(BK == 16, "staging assumes BK==16");
    __shared__ float As[BK][BM + 4];
    __shared__ float Ws[BK][BN + 4];
    const int tid = threadIdx.x;
    const int tx = tid & 15, ty = tid >> 4;
    const int m0 = blockIdx.y * BM, n0 = blockIdx.x * BN;
    const int k0 = blockIdx.z * kLen;

    float acc[TM][TN];
    #pragma unroll
    for (int i = 0; i < TM; i++)
        #pragma unroll
        for (int j = 0; j < TN; j++) acc[i][j] = 0.f;

    for (int kk = k0; kk < k0 + kLen; kk += BK) {
        for (int idx = tid; idx < BM * BK; idx += 256) {
            int rr = idx >> 4, cc = idx & 15;
            As[cc][rr] = A[(size_t)(m0 + rr) * lda + kk + cc];
        }
        for (int idx = tid; idx < BN * BK; idx += 256) {
            int rr = idx >> 4, cc = idx & 15;
            Ws[cc][rr] = W[(size_t)(n0 + rr) * ldw + kk + cc];
        }
        __syncthreads();
        #pragma unroll
        for (int k = 0; k < BK; k++) {
            float a[TM], b[TN];
            #pragma unroll
            for (int i = 0; i < TM; i++) a[i] = As[k][ty * TM + i];
            #pragma unroll
            for (int j = 0; j < TN; j++) b[j] = Ws[k][tx * TN + j];
            #pragma unroll
            for (int i = 0; i < TM; i++)
                #pragma unroll
                for (int j = 0; j < TN; j++) acc[i][j] = fmaf(a[i], b[j], acc[i][j]);
        }
        __syncthreads();
    }

    #pragma unroll
    for (int i = 0; i < TM; i++) {
        int row = m0 + ty * TM + i;
        #pragma unroll
        for (int j = 0; j < TN; j++) {
            int col = n0 + tx * TN + j;
            if (EPI == 1) {
                atomicAdd(&C[(size_t)row * ldc + col], acc[i][j]);
            } else if (EPI == 2) {
                float v = acc[i][j] + bias[col];
                C[(size_t)row * ldc + col] = fmaxf(v, 0.f) + log1pf(__expf(-fabsf(v)));
            } else {
                C[(size_t)row * ldc + col] = acc[i][j];
            }
        }
    }
}

// ---------------------------------------------------------------------------
// causal depthwise conv (width 4) + silu
// ---------------------------------------------------------------------------
__global__ __launch_bounds__(256) void conv_silu_kernel(
    const float* __restrict__ xz, const float* __restrict__ cw,
    const float* __restrict__ cb, float* __restrict__ u)
{
    int idx = blockIdx.x * 256 + threadIdx.x;   // over MTOK*DINNER
    int d = idx % DINNER;
    int r = idx / DINNER;          // b*SEQLEN + l
    int l = r & (SEQLEN - 1);
    const float* base = xz + (size_t)r * (2 * DINNER) + d;
    float acc = cb[d];
    float w0 = cw[d * 4 + 0], w1 = cw[d * 4 + 1], w2 = cw[d * 4 + 2], w3 = cw[d * 4 + 3];
    if (l >= 3) acc = fmaf(w0, base[-3 * 2 * DINNER], acc);
    if (l >= 2) acc = fmaf(w1, base[-2 * 2 * DINNER], acc);
    if (l >= 1) acc = fmaf(w2, base[-1 * 2 * DINNER], acc);
    acc = fmaf(w3, base[0], acc);
    u[idx] = acc / (1.f + __expf(-acc));
}

// ---------------------------------------------------------------------------
// Chunked parallel scan (3 passes). pass3 emits y pre-split as bf16 hi/lo.
// ---------------------------------------------------------------------------
__global__ __launch_bounds__(256, 4) void scan_pass1(
    const float* __restrict__ delta, const float* __restrict__ u,
    const float* __restrict__ xdbl, const float* __restrict__ A_log,
    float* __restrict__ pbuf, float* __restrict__ qbuf)
{
    int gid = blockIdx.x * 256 + threadIdx.x;  // BATCH*NCHUNK*DINNER
    int d = gid % DINNER;
    int r = gid / DINNER;
    int chunk = r & (NCHUNK - 1);
    int b = r >> 5;
    float Arow[16], p[16], q[16];
    #pragma unroll
    for (int n = 0; n < 16; n++) {
        Arow[n] = -__expf(A_log[d * 16 + n]);
        p[n] = 1.f;
        q[n] = 0.f;
    }
    const float* drow = delta + (size_t)b * SEQLEN * DINNER + d;
    const float* urow = u + (size_t)b * SEQLEN * DINNER + d;
    int t0 = chunk * CLEN;
    for (int i = 0; i < CLEN; i++) {
        int t = t0 + i;
        float dl = drow[(size_t)t * DINNER];
        float uu = urow[(size_t)t * DINNER];
        float du = dl * uu;
        const float* Bp = xdbl + (size_t)(b * SEQLEN + t) * XDIM + DTRANK;
        #pragma unroll
        for (int n = 0; n < 16; n++) {
            float dA = __expf(dl * Arow[n]);
            q[n] = fmaf(dA, q[n], du * Bp[n]);
            p[n] *= dA;
        }
    }
    size_t off = (size_t)((chunk * BATCH + b) * 16) * DINNER + d;
    #pragma unroll
    for (int n = 0; n < 16; n++) {
        pbuf[off + (size_t)n * DINNER] = p[n];
        qbuf[off + (size_t)n * DINNER] = q[n];
    }
}

__global__ __launch_bounds__(256) void scan_pass2(
    const float* __restrict__ pbuf, const float* __restrict__ qbuf,
    float* __restrict__ hinit)
{
    int gid = blockIdx.x * 256 + threadIdx.x;   // BATCH*16*DINNER
    float h = 0.f;
    for (int c = 0; c < NCHUNK; c++) {
        size_t o = (size_t)c * CHSTRIDE + gid;
        hinit[o] = h;
        h = fmaf(pbuf[o], h, qbuf[o]);
    }
}

__global__ __launch_bounds__(256, 4) void scan_pass3(
    const float* __restrict__ delta, const float* __restrict__ u,
    const float* __restrict__ xdbl, const float* __restrict__ xz,
    const float* __restrict__ A_log, const float* __restrict__ Dp,
    const float* __restrict__ hinit,
    unsigned short* __restrict__ yh, unsigned short* __restrict__ yl)
{
    int gid = blockIdx.x * 256 + threadIdx.x;
    int d = gid % DINNER;
    int r = gid / DINNER;
    int chunk = r & (NCHUNK - 1);
    int b = r >> 5;
    float Arow[16], h[16];
    #pragma unroll
    for (int n = 0; n < 16; n++) Arow[n] = -__expf(A_log[d * 16 + n]);
    size_t hoff = (size_t)chunk * CHSTRIDE + (size_t)(b * 16) * DINNER + d;
    #pragma unroll
    for (int n = 0; n < 16; n++) h[n] = hinit[hoff + (size_t)n * DINNER];
    float Dpar = Dp[d];
    const float* drow = delta + (size_t)b * SEQLEN * DINNER + d;
    const float* urow = u + (size_t)b * SEQLEN * DINNER + d;
    int t0 = chunk * CLEN;
    for (int i = 0; i < CLEN; i++) {
        int t = t0 + i;
        float dl = drow[(size_t)t * DINNER];
        float uu = urow[(size_t)t * DINNER];
        float du = dl * uu;
        const float* Bp = xdbl + (size_t)(b * SEQLEN + t) * XDIM + DTRANK;
        float yt = 0.f;
        #pragma unroll
        for (int n = 0; n < 16; n++) {
            float dA = __expf(dl * Arow[n]);
            h[n] = fmaf(dA, h[n], du * Bp[n]);
            yt = fmaf(h[n], Bp[16 + n], yt);
        }
        yt = fmaf(uu, Dpar, yt);
        float z = xz[(size_t)(b * SEQLEN + t) * (2 * DINNER) + DINNER + d];
        float sz = z / (1.f + __expf(-z));
        float yv = yt * sz;
        unsigned short hh, ll;
        splitbf(yv, hh, ll);
        size_t o = (size_t)(b * SEQLEN + t) * DINNER + d;
        yh[o] = hh;
        yl[o] = ll;
    }
}

// ---------------------------------------------------------------------------
extern "C" void kernel_launch(void* const* d_in, const int* in_sizes, int n_in,
                              void* d_out, int out_size, void* d_ws, size_t ws_size,
                              hipStream_t stream) {
    const float* x    = (const float*)d_in[0];
    const float* ipw  = (const float*)d_in[1];
    const float* cw   = (const float*)d_in[2];
    const float* cb   = (const float*)d_in[3];
    const float* xpw  = (const float*)d_in[4];
    const float* dpw  = (const float*)d_in[5];
    const float* dpb  = (const float*)d_in[6];
    const float* alog = (const float*)d_in[7];
    const float* dpar = (const float*)d_in[8];
    const float* opw  = (const float*)d_in[9];
    float* out = (float*)d_out;

    char* ws = (char*)d_ws;
    float* xz    = (float*)ws;            ws += (size_t)MTOK * 2 * DINNER * 4;   // 25.2 MB
    float* u     = (float*)ws;            ws += (size_t)MTOK * DINNER * 4;       // 12.6 MB
    float* xdbl  = (float*)ws;            ws += (size_t)MTOK * XDIM * 4;         // 0.66 MB
    float* delta = (float*)ws;            ws += (size_t)MTOK * DINNER * 4;       // 12.6 MB
    float* pbuf  = (float*)ws;            ws += (size_t)NCHUNK * CHSTRIDE * 4;   // 6.3 MB
    float* qbuf  = (float*)ws;            ws += (size_t)NCHUNK * CHSTRIDE * 4;
    float* hinit = (float*)ws;            ws += (size_t)NCHUNK * CHSTRIDE * 4;
    float* part  = (float*)ws;            ws += (size_t)4 * MTOK * DMODEL * 4;   // 25.2 MB
    unsigned short* ah  = (unsigned short*)ws; ws += (size_t)MTOK * DMODEL * 2;  // 3.1 MB
    unsigned short* al  = (unsigned short*)ws; ws += (size_t)MTOK * DMODEL * 2;
    unsigned short* yh  = (unsigned short*)ws; ws += (size_t)MTOK * DINNER * 2;  // 6.3 MB
    unsigned short* yl  = (unsigned short*)ws; ws += (size_t)MTOK * DINNER * 2;
    unsigned short* wih = (unsigned short*)ws; ws += (size_t)2 * DINNER * DMODEL * 2; // 4.7 MB
    unsigned short* wil = (unsigned short*)ws; ws += (size_t)2 * DINNER * DMODEL * 2;
    unsigned short* woh = (unsigned short*)ws; ws += (size_t)DMODEL * DINNER * 2;     // 2.4 MB
    unsigned short* wol = (unsigned short*)ws; ws += (size_t)DMODEL * DINNER * 2;

    for (int L = 0; L < NL; L++) {
        const float* ipw_l  = ipw  + (size_t)L * 2 * DINNER * DMODEL;
        const float* cw_l   = cw   + (size_t)L * DINNER * DCONV;
        const float* cb_l   = cb   + (size_t)L * DINNER;
        const float* xpw_l  = xpw  + (size_t)L * XDIM * DINNER;
        const float* dpw_l  = dpw  + (size_t)L * DINNER * DTRANK;
        const float* dpb_l  = dpb  + (size_t)L * DINNER;
        const float* alog_l = alog + (size_t)L * DINNER * DSTATE;
        const float* dpar_l = dpar + (size_t)L * DINNER;
        const float* opw_l  = opw  + (size_t)L * DMODEL * DINNER;

        // weight splits for this layer
        {
            int n4 = 2 * DINNER * DMODEL / 4;
            split_kernel<<<(n4 + 255) / 256, 256, 0, stream>>>(ipw_l, wih, wil, n4);
        }
        {
            int n4 = DMODEL * DINNER / 4;
            split_kernel<<<(n4 + 255) / 256, 256, 0, stream>>>(opw_l, woh, wol, n4);
        }
        if (L == 0) {
            int n4 = MTOK * DMODEL / 4;
            split_kernel<<<(n4 + 255) / 256, 256, 0, stream>>>(x, ah, al, n4);
        }

        // GEMM1: xz[2048,3072] = A @ ipw^T   (pre-split bf16, MFMA)
        gemm_pre<128, 128><<<dim3(2 * DINNER / 128, MTOK / 128, 1), 256, 0, stream>>>(
            ah, al, DMODEL, wih, wil, DMODEL, xz, 2 * DINNER, DMODEL, 0);

        // conv + silu -> u
        conv_silu_kernel<<<(MTOK * DINNER) / 256, 256, 0, stream>>>(xz, cw_l, cb_l, u);

        // GEMM2 (split-K, atomic): xdbl[2048,80] = u @ xpw^T
        hipMemsetAsync(xdbl, 0, (size_t)MTOK * XDIM * sizeof(float), stream);
        gemm_f32<64, 80, 16, 4, 5, 1><<<dim3(1, MTOK / 64, 8), 256, 0, stream>>>(
            u, DINNER, xpw_l, DINNER, xdbl, XDIM, DINNER / 8, nullptr);

        // GEMM3: delta = softplus(xdbl[:, :48] @ dpw^T + dpb)
        gemm_f32<64, 64, 16, 4, 4, 2><<<dim3(DINNER / 64, MTOK / 64, 1), 256, 0, stream>>>(
            xdbl, XDIM, dpw_l, DTRANK, delta, DINNER, DTRANK, dpb_l);

        // chunked scan; pass3 emits y as bf16 hi/lo
        scan_pass1<<<(BATCH * NCHUNK * DINNER) / 256, 256, 0, stream>>>(
            delta, u, xdbl, alog_l, pbuf, qbuf);
        scan_pass2<<<CHSTRIDE / 256, 256, 0, stream>>>(pbuf, qbuf, hinit);
        scan_pass3<<<(BATCH * NCHUNK * DINNER) / 256, 256, 0, stream>>>(
            delta, u, xdbl, xz, alog_l, dpar_l, hinit, yh, yl);

        // GEMM4 (split-K=4): part[z][2048,768] = y @ opw^T
        gemm_pre<128, 128><<<dim3(DMODEL / 128, MTOK / 128, 4), 256, 0, stream>>>(
            yh, yl, DINNER, woh, wol, DINNER, part, DMODEL,
            DINNER / 4, (size_t)MTOK * DMODEL);

        // reduce split-K; L<3 -> next layer's A (bf16 hi/lo), L==3 -> fp32 out
        int rblocks = MTOK * DMODEL / 4 / 256;
        if (L == NL - 1) {
            reduce4<0><<<rblocks, 256, 0, stream>>>(part, out, nullptr, nullptr);
        } else {
            reduce4<1><<<rblocks, 256, 0, stream>>>(part, nullptr, ah, al);
        }
    }
    (void)in_sizes; (void)n_in; (void)out_size; (void)ws_size;
}

// Round 3
// 959.423 us; speedup vs baseline: 1.6339x; 1.1786x over previous
//
#include <hip/hip_runtime.h>
#include <math.h>

#define NL 4
#define DMODEL 768
#define DINNER 1536
#define DSTATE 16
#define DCONV 4
#define DTRANK 48
#define BATCH 2
#define SEQLEN 1024
#define MTOK (BATCH*SEQLEN)      // 2048
#define XDIM 80                  // DTRANK + 2*DSTATE
#define NCHUNK 32
#define CLEN 32                  // SEQLEN/NCHUNK
#define CHSTRIDE (BATCH*16*DINNER)   // 49152
#define KPAD 64                  // DTRANK padded for MFMA
#define NPAD 96                  // XDIM padded for MFMA (3x32)
#define KS2 16                   // split-K slices for GEMM2

typedef __bf16 bf16x8 __attribute__((ext_vector_type(8)));
typedef float f32x4 __attribute__((ext_vector_type(4)));

__device__ __forceinline__ void splitbf(float f, unsigned short& hi, unsigned short& lo) {
    unsigned uh = __float_as_uint(f);
    unsigned rh = uh + (0x7fffu + ((uh >> 16) & 1u));
    unsigned short h = (unsigned short)(rh >> 16);
    float fh = __uint_as_float(((unsigned)h) << 16);
    float r = f - fh;
    unsigned ul = __float_as_uint(r);
    unsigned rl = ul + (0x7fffu + ((ul >> 16) & 1u));
    hi = h;
    lo = (unsigned short)(rl >> 16);
}

__device__ __forceinline__ float bf2f(unsigned short h) {
    return __uint_as_float(((unsigned)h) << 16);
}

__device__ __forceinline__ void gload_lds16(const void* g, void* l) {
    __builtin_amdgcn_global_load_lds(
        (const __attribute__((address_space(1))) unsigned*)g,
        (__attribute__((address_space(3))) unsigned*)l, 16, 0, 0);
}

// ---------------------------------------------------------------------------
// elementwise fp32 -> (bf16 hi, bf16 lo) split, float4 vectorized
// ---------------------------------------------------------------------------
__global__ __launch_bounds__(256) void split_kernel(
    const float* __restrict__ in, unsigned short* __restrict__ hi,
    unsigned short* __restrict__ lo, int n4)
{
    int i = blockIdx.x * 256 + threadIdx.x;
    if (i >= n4) return;
    float4 v = ((const float4*)in)[i];
    ushort4 h, l;
    splitbf(v.x, h.x, l.x);
    splitbf(v.y, h.y, l.y);
    splitbf(v.z, h.z, l.z);
    splitbf(v.w, h.w, l.w);
    ((ushort4*)hi)[i] = h;
    ((ushort4*)lo)[i] = l;
}

// split dpw [DINNER,48] -> hi/lo [DINNER,KPAD] with zero pad cols 48..63
__global__ __launch_bounds__(256) void split_pad_kernel(
    const float* __restrict__ in, unsigned short* __restrict__ hi,
    unsigned short* __restrict__ lo)
{
    int i = blockIdx.x * 256 + threadIdx.x;   // over DINNER*KPAD/4
    if (i >= DINNER * KPAD / 4) return;
    int e = i * 4;
    int row = e >> 6, col = e & 63;
    ushort4 h = {0, 0, 0, 0}, l = {0, 0, 0, 0};
    if (col < DTRANK) {
        float4 v = *(const float4*)(in + (size_t)row * DTRANK + col);
        splitbf(v.x, h.x, l.x);
        splitbf(v.y, h.y, l.y);
        splitbf(v.z, h.z, l.z);
        splitbf(v.w, h.w, l.w);
    }
    ((ushort4*)hi)[i] = h;
    ((ushort4*)lo)[i] = l;
}

// ---------------------------------------------------------------------------
// Pre-split 3-pass bf16 MFMA GEMM (m97 structure):
// C[M,N] = (Ah+Al)[M,K] @ (Wh+Wl)[N,K]^T  (dropping Al*Wl)
// BMxBN block tile, BK=32, 4 waves (2x2), global_load_lds width=16 staging.
// blockIdx.z = split-K slice; C += z*zstride. Cols >= nclip are not stored.
// EPI 0: plain store; EPI 2: softplus(acc + bias[col]).
// ---------------------------------------------------------------------------
template<int BM, int BN, int EPI>
__global__ __launch_bounds__(256, 2) void gemm_pre(
    const unsigned short* __restrict__ Ah, const unsigned short* __restrict__ Al, int lda,
    const unsigned short* __restrict__ Wh, const unsigned short* __restrict__ Wl, int ldw,
    float* __restrict__ C, int ldc, int Klen, size_t zstride, int nclip,
    const float* __restrict__ bias)
{
    constexpr int BK = 32;
    constexpr int MT = BM / 32, NT = BN / 32;
    constexpr int ACH = BM * 4;   // 16B chunks per A tile
    constexpr int WCH = BN * 4;
    __shared__ unsigned short sAh[BM * BK];
    __shared__ unsigned short sAl[BM * BK];
    __shared__ unsigned short sWh[BN * BK];
    __shared__ unsigned short sWl[BN * BK];

    const int tid = threadIdx.x;
    const int m0 = blockIdx.y * BM, n0 = blockIdx.x * BN;
    const int kbase = blockIdx.z * Klen;
    C += (size_t)blockIdx.z * zstride;
    const int lane = tid & 63, wave = tid >> 6;
    const int wr = wave >> 1, wc = wave & 1;
    const int wm0 = wr * (BM / 2), wn0 = wc * (BN / 2);
    const int lrow = lane & 15, lq = lane >> 4;

    f32x4 acc[MT][NT];
    #pragma unroll
    for (int mt = 0; mt < MT; mt++)
        #pragma unroll
        for (int nt = 0; nt < NT; nt++) {
            f32x4 z = {0.f, 0.f, 0.f, 0.f};
            acc[mt][nt] = z;
        }

    for (int k0 = kbase; k0 < kbase + Klen; k0 += BK) {
        // stage tiles: row-major [rows][32 bf16], 4x 16B chunks per row;
        // lane-linear chunk order == LDS layout (global_load_lds constraint)
        #pragma unroll
        for (int i = 0; i < (ACH + 255) / 256; i++) {
            int chunk = i * 256 + tid;
            if (ACH % 256 == 0 || chunk < ACH) {
                int r = chunk >> 2, c = (chunk & 3) * 8;
                size_t goff = (size_t)(m0 + r) * lda + k0 + c;
                gload_lds16(Ah + goff, &sAh[chunk * 8]);
                gload_lds16(Al + goff, &sAl[chunk * 8]);
            }
        }
        #pragma unroll
        for (int i = 0; i < (WCH + 255) / 256; i++) {
            int chunk = i * 256 + tid;
            if (WCH % 256 == 0 || chunk < WCH) {
                int r = chunk >> 2, c = (chunk & 3) * 8;
                size_t goff = (size_t)(n0 + r) * ldw + k0 + c;
                gload_lds16(Wh + goff, &sWh[chunk * 8]);
                gload_lds16(Wl + goff, &sWl[chunk * 8]);
            }
        }
        __syncthreads();

        bf16x8 fah[MT], fal[MT], fwh[NT], fwl[NT];
        #pragma unroll
        for (int mt = 0; mt < MT; mt++) {
            int off = (wm0 + mt * 16 + lrow) * BK + lq * 8;
            fah[mt] = *(const bf16x8*)&sAh[off];
            fal[mt] = *(const bf16x8*)&sAl[off];
        }
        #pragma unroll
        for (int nt = 0; nt < NT; nt++) {
            int off = (wn0 + nt * 16 + lrow) * BK + lq * 8;
            fwh[nt] = *(const bf16x8*)&sWh[off];
            fwl[nt] = *(const bf16x8*)&sWl[off];
        }
        #pragma unroll
        for (int mt = 0; mt < MT; mt++)
            #pragma unroll
            for (int nt = 0; nt < NT; nt++) {
                acc[mt][nt] = __builtin_amdgcn_mfma_f32_16x16x32_bf16(fah[mt], fwh[nt], acc[mt][nt], 0, 0, 0);
                acc[mt][nt] = __builtin_amdgcn_mfma_f32_16x16x32_bf16(fah[mt], fwl[nt], acc[mt][nt], 0, 0, 0);
                acc[mt][nt] = __builtin_amdgcn_mfma_f32_16x16x32_bf16(fal[mt], fwh[nt], acc[mt][nt], 0, 0, 0);
            }
        __syncthreads();
    }

    // C/D layout: col = lane&15, row = (lane>>4)*4 + reg   [measured m89/m91]
    #pragma unroll
    for (int mt = 0; mt < MT; mt++)
        #pragma unroll
        for (int nt = 0; nt < NT; nt++)
            #pragma unroll
            for (int i = 0; i < 4; i++) {
                int row = m0 + wm0 + mt * 16 + lq * 4 + i;
                int col = n0 + wn0 + nt * 16 + lrow;
                float v = acc[mt][nt][i];
                if (EPI == 2) {
                    float t = v + bias[col];
                    v = fmaxf(t, 0.f) + log1pf(__expf(-fabsf(t)));
                }
                if (col < nclip) C[(size_t)row * ldc + col] = v;
            }
}

// ---------------------------------------------------------------------------
// split-K reduce (4 slices) + optional bf16 hi/lo split for next-layer A
// MODE 0: write fp32 only; MODE 1: write hi/lo only
// ---------------------------------------------------------------------------
template<int MODE>
__global__ __launch_bounds__(256) void reduce4(
    const float* __restrict__ part, float* __restrict__ dst,
    unsigned short* __restrict__ hi, unsigned short* __restrict__ lo)
{
    constexpr size_t S = (size_t)MTOK * DMODEL / 4;
    int i = blockIdx.x * 256 + threadIdx.x;
    const float4* p = (const float4*)part;
    float4 a = p[i], b = p[i + S], c = p[i + 2 * S], d = p[i + 3 * S];
    float4 s = {a.x + b.x + c.x + d.x, a.y + b.y + c.y + d.y,
                a.z + b.z + c.z + d.z, a.w + b.w + c.w + d.w};
    if (MODE == 0) {
        ((float4*)dst)[i] = s;
    } else {
        ushort4 h, l;
        splitbf(s.x, h.x, l.x);
        splitbf(s.y, h.y, l.y);
        splitbf(s.z, h.z, l.z);
        splitbf(s.w, h.w, l.w);
        ((ushort4*)hi)[i] = h;
        ((ushort4*)lo)[i] = l;
    }
}

// ---------------------------------------------------------------------------
// GEMM2 reduce: sum KS2 slices of part[z][MTOK][XDIM] -> xdbl fp32;
// also emit dt cols (<48) pre-split into [MTOK][KPAD] hi/lo (pad cols via
// split_pad'd weights contribute 0, so they may stay unwritten here only if
// zeroed; we zero them explicitly below by writing the full padded row).
// ---------------------------------------------------------------------------
__global__ __launch_bounds__(256) void reduce16(
    const float* __restrict__ part, float* __restrict__ xdbl,
    unsigned short* __restrict__ dth, unsigned short* __restrict__ dtl)
{
    constexpr int N4 = MTOK * XDIM / 4;      // 40960
    constexpr int S4 = MTOK * XDIM / 4;      // slice stride in float4
    int i = blockIdx.x * 256 + threadIdx.x;
    if (i >= N4) return;
    const float4* p = (const float4*)part;
    float4 s = {0.f, 0.f, 0.f, 0.f};
    #pragma unroll
    for (int z = 0; z < KS2; z++) {
        float4 v = p[(size_t)z * S4 + i];
        s.x += v.x; s.y += v.y; s.z += v.z; s.w += v.w;
    }
    ((float4*)xdbl)[i] = s;
    int e = i * 4;
    int col = e % XDIM, row = e / XDIM;
    if (col < DTRANK) {
        ushort4 h, l;
        splitbf(s.x, h.x, l.x);
        splitbf(s.y, h.y, l.y);
        splitbf(s.z, h.z, l.z);
        splitbf(s.w, h.w, l.w);
        int o = (row * KPAD + col) / 4;
        ((ushort4*)dth)[o] = h;
        ((ushort4*)dtl)[o] = l;
    }
}

// zero the dt pad cols once per layer (cols 48..63 of [MTOK][KPAD])
__global__ __launch_bounds__(256) void zero_dtpad(
    unsigned short* __restrict__ dth, unsigned short* __restrict__ dtl)
{
    int i = blockIdx.x * 256 + threadIdx.x;   // MTOK * 16 / 4 = 8192
    int e = i * 4;
    int row = e >> 4, col = DTRANK + (e & 15);
    int o = (row * KPAD + col) / 4;
    ushort4 z = {0, 0, 0, 0};
    ((ushort4*)dth)[o] = z;
    ((ushort4*)dtl)[o] = z;
}

// ---------------------------------------------------------------------------
// causal depthwise conv (width 4) + silu -> u emitted as bf16 hi/lo
// ---------------------------------------------------------------------------
__global__ __launch_bounds__(256) void conv_silu_kernel(
    const float* __restrict__ xz, const float* __restrict__ cw,
    const float* __restrict__ cb,
    unsigned short* __restrict__ uh, unsigned short* __restrict__ ul)
{
    int idx = blockIdx.x * 256 + threadIdx.x;   // over MTOK*DINNER
    int d = idx % DINNER;
    int r = idx / DINNER;          // b*SEQLEN + l
    int l = r & (SEQLEN - 1);
    const float* base = xz + (size_t)r * (2 * DINNER) + d;
    float acc = cb[d];
    float w0 = cw[d * 4 + 0], w1 = cw[d * 4 + 1], w2 = cw[d * 4 + 2], w3 = cw[d * 4 + 3];
    if (l >= 3) acc = fmaf(w0, base[-3 * 2 * DINNER], acc);
    if (l >= 2) acc = fmaf(w1, base[-2 * 2 * DINNER], acc);
    if (l >= 1) acc = fmaf(w2, base[-1 * 2 * DINNER], acc);
    acc = fmaf(w3, base[0], acc);
    float uv = acc / (1.f + __expf(-acc));
    unsigned short h, lo_;
    splitbf(uv, h, lo_);
    uh[idx] = h;
    ul[idx] = lo_;
}

// ---------------------------------------------------------------------------
// Chunked parallel scan (3 passes). u reconstructed from hi/lo bf16.
// ---------------------------------------------------------------------------
__global__ __launch_bounds__(256, 4) void scan_pass1(
    const float* __restrict__ delta,
    const unsigned short* __restrict__ uh, const unsigned short* __restrict__ ul,
    const float* __restrict__ xdbl, const float* __restrict__ A_log,
    float* __restrict__ pbuf, float* __restrict__ qbuf)
{
    int gid = blockIdx.x * 256 + threadIdx.x;  // BATCH*NCHUNK*DINNER
    int d = gid % DINNER;
    int r = gid / DINNER;
    int chunk = r & (NCHUNK - 1);
    int b = r >> 5;
    float Arow[16], p[16], q[16];
    #pragma unroll
    for (int n = 0; n < 16; n++) {
        Arow[n] = -__expf(A_log[d * 16 + n]);
        p[n] = 1.f;
        q[n] = 0.f;
    }
    size_t rowbase = (size_t)b * SEQLEN * DINNER + d;
    int t0 = chunk * CLEN;
    for (int i = 0; i < CLEN; i++) {
        int t = t0 + i;
        size_t o = rowbase + (size_t)t * DINNER;
        float dl = delta[o];
        float uu = bf2f(uh[o]) + bf2f(ul[o]);
        float du = dl * uu;
        const float* Bp = xdbl + (size_t)(b * SEQLEN + t) * XDIM + DTRANK;
        #pragma unroll
        for (int n = 0; n < 16; n++) {
            float dA = __expf(dl * Arow[n]);
            q[n] = fmaf(dA, q[n], du * Bp[n]);
            p[n] *= dA;
        }
    }
    size_t off = (size_t)((chunk * BATCH + b) * 16) * DINNER + d;
    #pragma unroll
    for (int n = 0; n < 16; n++) {
        pbuf[off + (size_t)n * DINNER] = p[n];
        qbuf[off + (size_t)n * DINNER] = q[n];
    }
}

__global__ __launch_bounds__(256) void scan_pass2(
    const float* __restrict__ pbuf, const float* __restrict__ qbuf,
    float* __restrict__ hinit)
{
    int gid = blockIdx.x * 256 + threadIdx.x;   // BATCH*16*DINNER
    float h = 0.f;
    for (int c = 0; c < NCHUNK; c++) {
        size_t o = (size_t)c * CHSTRIDE + gid;
        hinit[o] = h;
        h = fmaf(pbuf[o], h, qbuf[o]);
    }
}

__global__ __launch_bounds__(256, 4) void scan_pass3(
    const float* __restrict__ delta,
    const unsigned short* __restrict__ uh, const unsigned short* __restrict__ ul,
    const float* __restrict__ xdbl, const float* __restrict__ xz,
    const float* __restrict__ A_log, const float* __restrict__ Dp,
    const float* __restrict__ hinit,
    unsigned short* __restrict__ yh, unsigned short* __restrict__ yl)
{
    int gid = blockIdx.x * 256 + threadIdx.x;
    int d = gid % DINNER;
    int r = gid / DINNER;
    int chunk = r & (NCHUNK - 1);
    int b = r >> 5;
    float Arow[16], h[16];
    #pragma unroll
    for (int n = 0; n < 16; n++) Arow[n] = -__expf(A_log[d * 16 + n]);
    size_t hoff = (size_t)chunk * CHSTRIDE + (size_t)(b * 16) * DINNER + d;
    #pragma unroll
    for (int n = 0; n < 16; n++) h[n] = hinit[hoff + (size_t)n * DINNER];
    float Dpar = Dp[d];
    size_t rowbase = (size_t)b * SEQLEN * DINNER + d;
    int t0 = chunk * CLEN;
    for (int i = 0; i < CLEN; i++) {
        int t = t0 + i;
        size_t o = rowbase + (size_t)t * DINNER;
        float dl = delta[o];
        float uu = bf2f(uh[o]) + bf2f(ul[o]);
        float du = dl * uu;
        const float* Bp = xdbl + (size_t)(b * SEQLEN + t) * XDIM + DTRANK;
        float yt = 0.f;
        #pragma unroll
        for (int n = 0; n < 16; n++) {
            float dA = __expf(dl * Arow[n]);
            h[n] = fmaf(dA, h[n], du * Bp[n]);
            yt = fmaf(h[n], Bp[16 + n], yt);
        }
        yt = fmaf(uu, Dpar, yt);
        float z = xz[(size_t)(b * SEQLEN + t) * (2 * DINNER) + DINNER + d];
        float sz = z / (1.f + __expf(-z));
        float yv = yt * sz;
        unsigned short hh, ll;
        splitbf(yv, hh, ll);
        yh[o] = hh;
        yl[o] = ll;
    }
}

// ---------------------------------------------------------------------------
extern "C" void kernel_launch(void* const* d_in, const int* in_sizes, int n_in,
                              void* d_out, int out_size, void* d_ws, size_t ws_size,
                              hipStream_t stream) {
    const float* x    = (const float*)d_in[0];
    const float* ipw  = (const float*)d_in[1];
    const float* cw   = (const float*)d_in[2];
    const float* cb   = (const float*)d_in[3];
    const float* xpw  = (const float*)d_in[4];
    const float* dpw  = (const float*)d_in[5];
    const float* dpb  = (const float*)d_in[6];
    const float* alog = (const float*)d_in[7];
    const float* dpar = (const float*)d_in[8];
    const float* opw  = (const float*)d_in[9];
    float* out = (float*)d_out;

    char* ws = (char*)d_ws;
    float* xz    = (float*)ws;            ws += (size_t)MTOK * 2 * DINNER * 4;   // 25.2 MB
    float* delta = (float*)ws;            ws += (size_t)MTOK * DINNER * 4;       // 12.6 MB
    float* xdbl  = (float*)ws;            ws += (size_t)MTOK * XDIM * 4;         // 0.66 MB
    float* pbuf  = (float*)ws;            ws += (size_t)NCHUNK * CHSTRIDE * 4;   // 6.3 MB
    float* qbuf  = (float*)ws;            ws += (size_t)NCHUNK * CHSTRIDE * 4;
    float* hinit = (float*)ws;            ws += (size_t)NCHUNK * CHSTRIDE * 4;
    float* part  = (float*)ws;            ws += (size_t)4 * MTOK * DMODEL * 4;   // 25.2 MB (also GEMM2 partials: 16*MTOK*XDIM*4 = 10.5 MB fits)
    unsigned short* ah  = (unsigned short*)ws; ws += (size_t)MTOK * DMODEL * 2;  // 3.1 MB
    unsigned short* al  = (unsigned short*)ws; ws += (size_t)MTOK * DMODEL * 2;
    unsigned short* yh  = (unsigned short*)ws; ws += (size_t)MTOK * DINNER * 2;  // 6.3 MB
    unsigned short* yl  = (unsigned short*)ws; ws += (size_t)MTOK * DINNER * 2;
    unsigned short* uh  = (unsigned short*)ws; ws += (size_t)MTOK * DINNER * 2;  // 6.3 MB
    unsigned short* ul  = (unsigned short*)ws; ws += (size_t)MTOK * DINNER * 2;
    unsigned short* wih = (unsigned short*)ws; ws += (size_t)2 * DINNER * DMODEL * 2; // 4.7 MB
    unsigned short* wil = (unsigned short*)ws; ws += (size_t)2 * DINNER * DMODEL * 2;
    unsigned short* woh = (unsigned short*)ws; ws += (size_t)DMODEL * DINNER * 2;     // 2.4 MB
    unsigned short* wol = (unsigned short*)ws; ws += (size_t)DMODEL * DINNER * 2;
    unsigned short* wxh = (unsigned short*)ws; ws += (size_t)NPAD * DINNER * 2;       // 0.3 MB
    unsigned short* wxl = (unsigned short*)ws; ws += (size_t)NPAD * DINNER * 2;
    unsigned short* wdh = (unsigned short*)ws; ws += (size_t)DINNER * KPAD * 2;       // 0.2 MB
    unsigned short* wdl = (unsigned short*)ws; ws += (size_t)DINNER * KPAD * 2;
    unsigned short* dth = (unsigned short*)ws; ws += (size_t)MTOK * KPAD * 2;         // 0.26 MB
    unsigned short* dtl = (unsigned short*)ws; ws += (size_t)MTOK * KPAD * 2;

    for (int L = 0; L < NL; L++) {
        const float* ipw_l  = ipw  + (size_t)L * 2 * DINNER * DMODEL;
        const float* cw_l   = cw   + (size_t)L * DINNER * DCONV;
        const float* cb_l   = cb   + (size_t)L * DINNER;
        const float* xpw_l  = xpw  + (size_t)L * XDIM * DINNER;
        const float* dpw_l  = dpw  + (size_t)L * DINNER * DTRANK;
        const float* dpb_l  = dpb  + (size_t)L * DINNER;
        const float* alog_l = alog + (size_t)L * DINNER * DSTATE;
        const float* dpar_l = dpar + (size_t)L * DINNER;
        const float* opw_l  = opw  + (size_t)L * DMODEL * DINNER;

        // weight splits for this layer
        {
            int n4 = 2 * DINNER * DMODEL / 4;
            split_kernel<<<(n4 + 255) / 256, 256, 0, stream>>>(ipw_l, wih, wil, n4);
        }
        {
            int n4 = DMODEL * DINNER / 4;
            split_kernel<<<(n4 + 255) / 256, 256, 0, stream>>>(opw_l, woh, wol, n4);
        }
        // xpw split: zero the 96-row padded buffers, then fill rows 0..79
        hipMemsetAsync(wxh, 0, (size_t)NPAD * DINNER * 2, stream);
        hipMemsetAsync(wxl, 0, (size_t)NPAD * DINNER * 2, stream);
        {
            int n4 = XDIM * DINNER / 4;
            split_kernel<<<(n4 + 255) / 256, 256, 0, stream>>>(xpw_l, wxh, wxl, n4);
        }
        // dpw split with K-pad 48->64 (pad cols zeroed)
        {
            int n4 = DINNER * KPAD / 4;
            split_pad_kernel<<<(n4 + 255) / 256, 256, 0, stream>>>(dpw_l, wdh, wdl);
        }
        zero_dtpad<<<(MTOK * 16 / 4) / 256, 256, 0, stream>>>(dth, dtl);
        if (L == 0) {
            int n4 = MTOK * DMODEL / 4;
            split_kernel<<<(n4 + 255) / 256, 256, 0, stream>>>(x, ah, al, n4);
        }

        // GEMM1: xz[2048,3072] = A @ ipw^T   (pre-split bf16, MFMA)
        gemm_pre<128, 128, 0><<<dim3(2 * DINNER / 128, MTOK / 128, 1), 256, 0, stream>>>(
            ah, al, DMODEL, wih, wil, DMODEL, xz, 2 * DINNER, DMODEL, 0, 1 << 30, nullptr);

        // conv + silu -> u (bf16 hi/lo)
        conv_silu_kernel<<<(MTOK * DINNER) / 256, 256, 0, stream>>>(xz, cw_l, cb_l, uh, ul);

        // GEMM2 (split-K=16 partials): part[z][2048,80] = u-slice @ xpw-slice^T
        gemm_pre<128, NPAD, 0><<<dim3(1, MTOK / 128, KS2), 256, 0, stream>>>(
            uh, ul, DINNER, wxh, wxl, DINNER, part, XDIM,
            DINNER / KS2, (size_t)MTOK * XDIM, XDIM, nullptr);
        reduce16<<<(MTOK * XDIM / 4 + 255) / 256, 256, 0, stream>>>(part, xdbl, dth, dtl);

        // GEMM3: delta = softplus(dt @ dpw^T + dpb)   (K padded to 64)
        gemm_pre<128, 128, 2><<<dim3(DINNER / 128, MTOK / 128, 1), 256, 0, stream>>>(
            dth, dtl, KPAD, wdh, wdl, KPAD, delta, DINNER, KPAD, 0, 1 << 30, dpb_l);

        // chunked scan; pass3 emits y as bf16 hi/lo
        scan_pass1<<<(BATCH * NCHUNK * DINNER) / 256, 256, 0, stream>>>(
            delta, uh, ul, xdbl, alog_l, pbuf, qbuf);
        scan_pass2<<<CHSTRIDE / 256, 256, 0, stream>>>(pbuf, qbuf, hinit);
        scan_pass3<<<(BATCH * NCHUNK * DINNER) / 256, 256, 0, stream>>>(
            delta, uh, ul, xdbl, xz, alog_l, dpar_l, hinit, yh, yl);

        // GEMM4 (split-K=4): part[z][2048,768] = y @ opw^T
        gemm_pre<128, 128, 0><<<dim3(DMODEL / 128, MTOK / 128, 4), 256, 0, stream>>>(
            yh, yl, DINNER, woh, wol, DINNER, part, DMODEL,
            DINNER / 4, (size_t)MTOK * DMODEL, 1 << 30, nullptr);

        // reduce split-K; L<3 -> next layer's A (bf16 hi/lo), L==3 -> fp32 out
        int rblocks = MTOK * DMODEL / 4 / 256;
        if (L == NL - 1) {
            reduce4<0><<<rblocks, 256, 0, stream>>>(part, out, nullptr, nullptr);
        } else {
            reduce4<1><<<rblocks, 256, 0, stream>>>(part, nullptr, ah, al);
        }
    }
    (void)in_sizes; (void)n_in; (void)out_size; (void)ws_size;
}

// Round 4
// 805.032 us; speedup vs baseline: 1.9473x; 1.1918x over previous
//
#include <hip/hip_runtime.h>
#include <math.h>

#define NL 4
#define DMODEL 768
#define DINNER 1536
#define DSTATE 16
#define DCONV 4
#define DTRANK 48
#define BATCH 2
#define SEQLEN 1024
#define MTOK (BATCH*SEQLEN)      // 2048
#define XDIM 80                  // DTRANK + 2*DSTATE
#define NCHUNK 64
#define NCSHIFT 6
#define CLEN 16                  // SEQLEN/NCHUNK
#define CHSTRIDE (BATCH*16*DINNER)   // 49152
#define KPAD 64                  // DTRANK padded for MFMA
#define NPAD 96                  // XDIM padded for MFMA (3x32)
#define KS2 16                   // split-K slices for GEMM2

typedef __bf16 bf16x8 __attribute__((ext_vector_type(8)));
typedef float f32x4 __attribute__((ext_vector_type(4)));

__device__ __forceinline__ void splitbf(float f, unsigned short& hi, unsigned short& lo) {
    unsigned uh = __float_as_uint(f);
    unsigned rh = uh + (0x7fffu + ((uh >> 16) & 1u));
    unsigned short h = (unsigned short)(rh >> 16);
    float fh = __uint_as_float(((unsigned)h) << 16);
    float r = f - fh;
    unsigned ul = __float_as_uint(r);
    unsigned rl = ul + (0x7fffu + ((ul >> 16) & 1u));
    hi = h;
    lo = (unsigned short)(rl >> 16);
}

__device__ __forceinline__ void splitbf4(float4 v, ushort4& h, ushort4& l) {
    splitbf(v.x, h.x, l.x);
    splitbf(v.y, h.y, l.y);
    splitbf(v.z, h.z, l.z);
    splitbf(v.w, h.w, l.w);
}

__device__ __forceinline__ float bf2f(unsigned short h) {
    return __uint_as_float(((unsigned)h) << 16);
}

__device__ __forceinline__ void gload_lds16(const void* g, void* l) {
    __builtin_amdgcn_global_load_lds(
        (const __attribute__((address_space(1))) unsigned*)g,
        (__attribute__((address_space(3))) unsigned*)l, 16, 0, 0);
}

// ---------------------------------------------------------------------------
// Per-layer prep: all weight splits (+padding) and dt pad-zero in ONE kernel.
// Range-dispatched over flat float4 indices. WITHX adds the layer-0 x split.
// ---------------------------------------------------------------------------
#define N_IPW (2 * DINNER * DMODEL / 4)   // 589824
#define N_OPW (DMODEL * DINNER / 4)       // 294912
#define N_XPW (NPAD * DINNER / 4)         // 36864
#define N_DPW (DINNER * KPAD / 4)         // 24576
#define N_DTP (MTOK * (KPAD - DTRANK) / 4)// 8192
#define N_PREP (N_IPW + N_OPW + N_XPW + N_DPW + N_DTP)        // 954368
#define N_XSPL (MTOK * DMODEL / 4)        // 393216

template<int WITHX>
__global__ __launch_bounds__(256) void prep_kernel(
    const float* __restrict__ ipw_l, const float* __restrict__ opw_l,
    const float* __restrict__ xpw_l, const float* __restrict__ dpw_l,
    const float* __restrict__ x,
    unsigned short* __restrict__ wih, unsigned short* __restrict__ wil,
    unsigned short* __restrict__ woh, unsigned short* __restrict__ wol,
    unsigned short* __restrict__ wxh, unsigned short* __restrict__ wxl,
    unsigned short* __restrict__ wdh, unsigned short* __restrict__ wdl,
    unsigned short* __restrict__ dth, unsigned short* __restrict__ dtl,
    unsigned short* __restrict__ ah, unsigned short* __restrict__ al)
{
    int i = blockIdx.x * 256 + threadIdx.x;
    if (i < N_IPW) {
        float4 v = ((const float4*)ipw_l)[i];
        ushort4 h, l;
        splitbf4(v, h, l);
        ((ushort4*)wih)[i] = h;
        ((ushort4*)wil)[i] = l;
        return;
    }
    i -= N_IPW;
    if (i < N_OPW) {
        float4 v = ((const float4*)opw_l)[i];
        ushort4 h, l;
        splitbf4(v, h, l);
        ((ushort4*)woh)[i] = h;
        ((ushort4*)wol)[i] = l;
        return;
    }
    i -= N_OPW;
    if (i < N_XPW) {
        int e = i * 4;
        int row = e / DINNER, col = e % DINNER;
        ushort4 h = {0, 0, 0, 0}, l = {0, 0, 0, 0};
        if (row < XDIM) {
            float4 v = *(const float4*)(xpw_l + (size_t)row * DINNER + col);
            splitbf4(v, h, l);
        }
        ((ushort4*)wxh)[i] = h;
        ((ushort4*)wxl)[i] = l;
        return;
    }
    i -= N_XPW;
    if (i < N_DPW) {
        int e = i * 4;
        int row = e >> 6, col = e & 63;
        ushort4 h = {0, 0, 0, 0}, l = {0, 0, 0, 0};
        if (col < DTRANK) {
            float4 v = *(const float4*)(dpw_l + (size_t)row * DTRANK + col);
            splitbf4(v, h, l);
        }
        ((ushort4*)wdh)[i] = h;
        ((ushort4*)wdl)[i] = l;
        return;
    }
    i -= N_DPW;
    if (i < N_DTP) {
        int e = i * 4;
        int row = e >> 4, col = DTRANK + (e & 15);
        int o = (row * KPAD + col) / 4;
        ushort4 z = {0, 0, 0, 0};
        ((ushort4*)dth)[o] = z;
        ((ushort4*)dtl)[o] = z;
        return;
    }
    if (WITHX) {
        i -= N_DTP;
        if (i < N_XSPL) {
            float4 v = ((const float4*)x)[i];
            ushort4 h, l;
            splitbf4(v, h, l);
            ((ushort4*)ah)[i] = h;
            ((ushort4*)al)[i] = l;
        }
    }
}

// ---------------------------------------------------------------------------
// Pre-split 3-pass bf16 MFMA GEMM (m97 structure):
// C[M,N] = (Ah+Al)[M,K] @ (Wh+Wl)[N,K]^T  (dropping Al*Wl)
// BMxBN block tile, BK=32, 4 waves (2x2), global_load_lds width=16 staging.
// blockIdx.z = split-K slice; C += z*zstride. Cols >= nclip are not stored.
// EPI 0: plain store; EPI 2: softplus(acc + bias[col]).
// ---------------------------------------------------------------------------
template<int BM, int BN, int EPI>
__global__ __launch_bounds__(256, 2) void gemm_pre(
    const unsigned short* __restrict__ Ah, const unsigned short* __restrict__ Al, int lda,
    const unsigned short* __restrict__ Wh, const unsigned short* __restrict__ Wl, int ldw,
    float* __restrict__ C, int ldc, int Klen, size_t zstride, int nclip,
    const float* __restrict__ bias)
{
    constexpr int BK = 32;
    constexpr int MT = BM / 32, NT = BN / 32;
    constexpr int ACH = BM * 4;   // 16B chunks per A tile
    constexpr int WCH = BN * 4;
    __shared__ unsigned short sAh[BM * BK];
    __shared__ unsigned short sAl[BM * BK];
    __shared__ unsigned short sWh[BN * BK];
    __shared__ unsigned short sWl[BN * BK];

    const int tid = threadIdx.x;
    const int m0 = blockIdx.y * BM, n0 = blockIdx.x * BN;
    const int kbase = blockIdx.z * Klen;
    C += (size_t)blockIdx.z * zstride;
    const int lane = tid & 63, wave = tid >> 6;
    const int wr = wave >> 1, wc = wave & 1;
    const int wm0 = wr * (BM / 2), wn0 = wc * (BN / 2);
    const int lrow = lane & 15, lq = lane >> 4;

    f32x4 acc[MT][NT];
    #pragma unroll
    for (int mt = 0; mt < MT; mt++)
        #pragma unroll
        for (int nt = 0; nt < NT; nt++) {
            f32x4 z = {0.f, 0.f, 0.f, 0.f};
            acc[mt][nt] = z;
        }

    for (int k0 = kbase; k0 < kbase + Klen; k0 += BK) {
        #pragma unroll
        for (int i = 0; i < (ACH + 255) / 256; i++) {
            int chunk = i * 256 + tid;
            if (ACH % 256 == 0 || chunk < ACH) {
                int r = chunk >> 2, c = (chunk & 3) * 8;
                size_t goff = (size_t)(m0 + r) * lda + k0 + c;
                gload_lds16(Ah + goff, &sAh[chunk * 8]);
                gload_lds16(Al + goff, &sAl[chunk * 8]);
            }
        }
        #pragma unroll
        for (int i = 0; i < (WCH + 255) / 256; i++) {
            int chunk = i * 256 + tid;
            if (WCH % 256 == 0 || chunk < WCH) {
                int r = chunk >> 2, c = (chunk & 3) * 8;
                size_t goff = (size_t)(n0 + r) * ldw + k0 + c;
                gload_lds16(Wh + goff, &sWh[chunk * 8]);
                gload_lds16(Wl + goff, &sWl[chunk * 8]);
            }
        }
        __syncthreads();

        bf16x8 fah[MT], fal[MT], fwh[NT], fwl[NT];
        #pragma unroll
        for (int mt = 0; mt < MT; mt++) {
            int off = (wm0 + mt * 16 + lrow) * BK + lq * 8;
            fah[mt] = *(const bf16x8*)&sAh[off];
            fal[mt] = *(const bf16x8*)&sAl[off];
        }
        #pragma unroll
        for (int nt = 0; nt < NT; nt++) {
            int off = (wn0 + nt * 16 + lrow) * BK + lq * 8;
            fwh[nt] = *(const bf16x8*)&sWh[off];
            fwl[nt] = *(const bf16x8*)&sWl[off];
        }
        #pragma unroll
        for (int mt = 0; mt < MT; mt++)
            #pragma unroll
            for (int nt = 0; nt < NT; nt++) {
                acc[mt][nt] = __builtin_amdgcn_mfma_f32_16x16x32_bf16(fah[mt], fwh[nt], acc[mt][nt], 0, 0, 0);
                acc[mt][nt] = __builtin_amdgcn_mfma_f32_16x16x32_bf16(fah[mt], fwl[nt], acc[mt][nt], 0, 0, 0);
                acc[mt][nt] = __builtin_amdgcn_mfma_f32_16x16x32_bf16(fal[mt], fwh[nt], acc[mt][nt], 0, 0, 0);
            }
        __syncthreads();
    }

    // C/D layout: col = lane&15, row = (lane>>4)*4 + reg   [measured m89/m91]
    #pragma unroll
    for (int mt = 0; mt < MT; mt++)
        #pragma unroll
        for (int nt = 0; nt < NT; nt++)
            #pragma unroll
            for (int i = 0; i < 4; i++) {
                int row = m0 + wm0 + mt * 16 + lq * 4 + i;
                int col = n0 + wn0 + nt * 16 + lrow;
                float v = acc[mt][nt][i];
                if (EPI == 2) {
                    float t = v + bias[col];
                    v = fmaxf(t, 0.f) + log1pf(__expf(-fabsf(t)));
                }
                if (col < nclip) C[(size_t)row * ldc + col] = v;
            }
}

// ---------------------------------------------------------------------------
// split-K reduce (4 slices) + optional bf16 hi/lo split for next-layer A
// ---------------------------------------------------------------------------
template<int MODE>
__global__ __launch_bounds__(256) void reduce4(
    const float* __restrict__ part, float* __restrict__ dst,
    unsigned short* __restrict__ hi, unsigned short* __restrict__ lo)
{
    constexpr size_t S = (size_t)MTOK * DMODEL / 4;
    int i = blockIdx.x * 256 + threadIdx.x;
    const float4* p = (const float4*)part;
    float4 a = p[i], b = p[i + S], c = p[i + 2 * S], d = p[i + 3 * S];
    float4 s = {a.x + b.x + c.x + d.x, a.y + b.y + c.y + d.y,
                a.z + b.z + c.z + d.z, a.w + b.w + c.w + d.w};
    if (MODE == 0) {
        ((float4*)dst)[i] = s;
    } else {
        ushort4 h, l;
        splitbf4(s, h, l);
        ((ushort4*)hi)[i] = h;
        ((ushort4*)lo)[i] = l;
    }
}

// ---------------------------------------------------------------------------
// GEMM2 reduce: sum KS2 slices -> xdbl fp32; emit dt cols pre-split (padded
// cols 48..63 were zeroed by prep_kernel).
// ---------------------------------------------------------------------------
__global__ __launch_bounds__(256) void reduce16(
    const float* __restrict__ part, float* __restrict__ xdbl,
    unsigned short* __restrict__ dth, unsigned short* __restrict__ dtl)
{
    constexpr int N4 = MTOK * XDIM / 4;      // 40960
    constexpr int S4 = MTOK * XDIM / 4;
    int i = blockIdx.x * 256 + threadIdx.x;
    if (i >= N4) return;
    const float4* p = (const float4*)part;
    float4 s = {0.f, 0.f, 0.f, 0.f};
    #pragma unroll
    for (int z = 0; z < KS2; z++) {
        float4 v = p[(size_t)z * S4 + i];
        s.x += v.x; s.y += v.y; s.z += v.z; s.w += v.w;
    }
    ((float4*)xdbl)[i] = s;
    int e = i * 4;
    int col = e % XDIM, row = e / XDIM;
    if (col < DTRANK) {
        ushort4 h, l;
        splitbf4(s, h, l);
        int o = (row * KPAD + col) / 4;
        ((ushort4*)dth)[o] = h;
        ((ushort4*)dtl)[o] = l;
    }
}

// ---------------------------------------------------------------------------
// causal depthwise conv (width 4) + silu -> u emitted as bf16 hi/lo
// ---------------------------------------------------------------------------
__global__ __launch_bounds__(256) void conv_silu_kernel(
    const float* __restrict__ xz, const float* __restrict__ cw,
    const float* __restrict__ cb,
    unsigned short* __restrict__ uh, unsigned short* __restrict__ ul)
{
    int idx = blockIdx.x * 256 + threadIdx.x;   // over MTOK*DINNER
    int d = idx % DINNER;
    int r = idx / DINNER;          // b*SEQLEN + l
    int l = r & (SEQLEN - 1);
    const float* base = xz + (size_t)r * (2 * DINNER) + d;
    float acc = cb[d];
    float w0 = cw[d * 4 + 0], w1 = cw[d * 4 + 1], w2 = cw[d * 4 + 2], w3 = cw[d * 4 + 3];
    if (l >= 3) acc = fmaf(w0, base[-3 * 2 * DINNER], acc);
    if (l >= 2) acc = fmaf(w1, base[-2 * 2 * DINNER], acc);
    if (l >= 1) acc = fmaf(w2, base[-1 * 2 * DINNER], acc);
    acc = fmaf(w3, base[0], acc);
    float uv = acc / (1.f + __expf(-acc));
    unsigned short h, lo_;
    splitbf(uv, h, lo_);
    uh[idx] = h;
    ul[idx] = lo_;
}

// ---------------------------------------------------------------------------
// Chunked parallel scan (3 passes), NCHUNK=64 for occupancy.
// ---------------------------------------------------------------------------
__global__ __launch_bounds__(256, 4) void scan_pass1(
    const float* __restrict__ delta,
    const unsigned short* __restrict__ uh, const unsigned short* __restrict__ ul,
    const float* __restrict__ xdbl, const float* __restrict__ A_log,
    float* __restrict__ pbuf, float* __restrict__ qbuf)
{
    int gid = blockIdx.x * 256 + threadIdx.x;  // BATCH*NCHUNK*DINNER
    int d = gid % DINNER;
    int r = gid / DINNER;
    int chunk = r & (NCHUNK - 1);
    int b = r >> NCSHIFT;
    float Arow[16], q[16];
    #pragma unroll
    for (int n = 0; n < 16; n++) {
        Arow[n] = -__expf(A_log[d * 16 + n]);
        q[n] = 0.f;
    }
    float sdl = 0.f;
    size_t rowbase = (size_t)b * SEQLEN * DINNER + d;
    int t0 = chunk * CLEN;
    #pragma unroll 2
    for (int i = 0; i < CLEN; i++) {
        int t = t0 + i;
        size_t o = rowbase + (size_t)t * DINNER;
        float dl = delta[o];
        float uu = bf2f(uh[o]) + bf2f(ul[o]);
        float du = dl * uu;
        sdl += dl;
        const float* Bp = xdbl + (size_t)(b * SEQLEN + t) * XDIM + DTRANK;
        #pragma unroll
        for (int n = 0; n < 16; n++) {
            float dA = __expf(dl * Arow[n]);
            q[n] = fmaf(dA, q[n], du * Bp[n]);
        }
    }
    size_t off = (size_t)((chunk * BATCH + b) * 16) * DINNER + d;
    #pragma unroll
    for (int n = 0; n < 16; n++) {
        pbuf[off + (size_t)n * DINNER] = __expf(Arow[n] * sdl);   // prod of dA
        qbuf[off + (size_t)n * DINNER] = q[n];
    }
}

__global__ __launch_bounds__(256) void scan_pass2(
    const float* __restrict__ pbuf, const float* __restrict__ qbuf,
    float* __restrict__ hinit)
{
    int gid = blockIdx.x * 256 + threadIdx.x;   // BATCH*16*DINNER
    float h = 0.f;
    #pragma unroll 4
    for (int c = 0; c < NCHUNK; c++) {
        size_t o = (size_t)c * CHSTRIDE + gid;
        hinit[o] = h;
        h = fmaf(pbuf[o], h, qbuf[o]);
    }
}

__global__ __launch_bounds__(256, 4) void scan_pass3(
    const float* __restrict__ delta,
    const unsigned short* __restrict__ uh, const unsigned short* __restrict__ ul,
    const float* __restrict__ xdbl, const float* __restrict__ xz,
    const float* __restrict__ A_log, const float* __restrict__ Dp,
    const float* __restrict__ hinit,
    unsigned short* __restrict__ yh, unsigned short* __restrict__ yl)
{
    int gid = blockIdx.x * 256 + threadIdx.x;
    int d = gid % DINNER;
    int r = gid / DINNER;
    int chunk = r & (NCHUNK - 1);
    int b = r >> NCSHIFT;
    float Arow[16], h[16];
    #pragma unroll
    for (int n = 0; n < 16; n++) Arow[n] = -__expf(A_log[d * 16 + n]);
    size_t hoff = (size_t)chunk * CHSTRIDE + (size_t)(b * 16) * DINNER + d;
    #pragma unroll
    for (int n = 0; n < 16; n++) h[n] = hinit[hoff + (size_t)n * DINNER];
    float Dpar = Dp[d];
    size_t rowbase = (size_t)b * SEQLEN * DINNER + d;
    int t0 = chunk * CLEN;
    #pragma unroll 2
    for (int i = 0; i < CLEN; i++) {
        int t = t0 + i;
        size_t o = rowbase + (size_t)t * DINNER;
        float dl = delta[o];
        float uu = bf2f(uh[o]) + bf2f(ul[o]);
        float du = dl * uu;
        const float* Bp = xdbl + (size_t)(b * SEQLEN + t) * XDIM + DTRANK;
        float yt = 0.f;
        #pragma unroll
        for (int n = 0; n < 16; n++) {
            float dA = __expf(dl * Arow[n]);
            h[n] = fmaf(dA, h[n], du * Bp[n]);
            yt = fmaf(h[n], Bp[16 + n], yt);
        }
        yt = fmaf(uu, Dpar, yt);
        float z = xz[(size_t)(b * SEQLEN + t) * (2 * DINNER) + DINNER + d];
        float sz = z / (1.f + __expf(-z));
        float yv = yt * sz;
        unsigned short hh, ll;
        splitbf(yv, hh, ll);
        yh[o] = hh;
        yl[o] = ll;
    }
}

// ---------------------------------------------------------------------------
extern "C" void kernel_launch(void* const* d_in, const int* in_sizes, int n_in,
                              void* d_out, int out_size, void* d_ws, size_t ws_size,
                              hipStream_t stream) {
    const float* x    = (const float*)d_in[0];
    const float* ipw  = (const float*)d_in[1];
    const float* cw   = (const float*)d_in[2];
    const float* cb   = (const float*)d_in[3];
    const float* xpw  = (const float*)d_in[4];
    const float* dpw  = (const float*)d_in[5];
    const float* dpb  = (const float*)d_in[6];
    const float* alog = (const float*)d_in[7];
    const float* dpar = (const float*)d_in[8];
    const float* opw  = (const float*)d_in[9];
    float* out = (float*)d_out;

    char* ws = (char*)d_ws;
    float* xz    = (float*)ws;            ws += (size_t)MTOK * 2 * DINNER * 4;   // 25.2 MB
    float* delta = (float*)ws;            ws += (size_t)MTOK * DINNER * 4;       // 12.6 MB
    float* xdbl  = (float*)ws;            ws += (size_t)MTOK * XDIM * 4;         // 0.66 MB
    float* pbuf  = (float*)ws;            ws += (size_t)NCHUNK * CHSTRIDE * 4;   // 12.6 MB
    float* qbuf  = (float*)ws;            ws += (size_t)NCHUNK * CHSTRIDE * 4;
    float* hinit = (float*)ws;            ws += (size_t)NCHUNK * CHSTRIDE * 4;
    float* part  = (float*)ws;            ws += (size_t)4 * MTOK * DMODEL * 4;   // 25.2 MB (also GEMM2 partials: 10.5 MB)
    unsigned short* ah  = (unsigned short*)ws; ws += (size_t)MTOK * DMODEL * 2;  // 3.1 MB
    unsigned short* al  = (unsigned short*)ws; ws += (size_t)MTOK * DMODEL * 2;
    unsigned short* yh  = (unsigned short*)ws; ws += (size_t)MTOK * DINNER * 2;  // 6.3 MB
    unsigned short* yl  = (unsigned short*)ws; ws += (size_t)MTOK * DINNER * 2;
    unsigned short* uh  = (unsigned short*)ws; ws += (size_t)MTOK * DINNER * 2;  // 6.3 MB
    unsigned short* ul  = (unsigned short*)ws; ws += (size_t)MTOK * DINNER * 2;
    unsigned short* wih = (unsigned short*)ws; ws += (size_t)2 * DINNER * DMODEL * 2; // 4.7 MB
    unsigned short* wil = (unsigned short*)ws; ws += (size_t)2 * DINNER * DMODEL * 2;
    unsigned short* woh = (unsigned short*)ws; ws += (size_t)DMODEL * DINNER * 2;     // 2.4 MB
    unsigned short* wol = (unsigned short*)ws; ws += (size_t)DMODEL * DINNER * 2;
    unsigned short* wxh = (unsigned short*)ws; ws += (size_t)NPAD * DINNER * 2;       // 0.3 MB
    unsigned short* wxl = (unsigned short*)ws; ws += (size_t)NPAD * DINNER * 2;
    unsigned short* wdh = (unsigned short*)ws; ws += (size_t)DINNER * KPAD * 2;       // 0.2 MB
    unsigned short* wdl = (unsigned short*)ws; ws += (size_t)DINNER * KPAD * 2;
    unsigned short* dth = (unsigned short*)ws; ws += (size_t)MTOK * KPAD * 2;         // 0.26 MB
    unsigned short* dtl = (unsigned short*)ws; ws += (size_t)MTOK * KPAD * 2;

    for (int L = 0; L < NL; L++) {
        const float* ipw_l  = ipw  + (size_t)L * 2 * DINNER * DMODEL;
        const float* cw_l   = cw   + (size_t)L * DINNER * DCONV;
        const float* cb_l   = cb   + (size_t)L * DINNER;
        const float* xpw_l  = xpw  + (size_t)L * XDIM * DINNER;
        const float* dpw_l  = dpw  + (size_t)L * DINNER * DTRANK;
        const float* dpb_l  = dpb  + (size_t)L * DINNER;
        const float* alog_l = alog + (size_t)L * DINNER * DSTATE;
        const float* dpar_l = dpar + (size_t)L * DINNER;
        const float* opw_l  = opw  + (size_t)L * DMODEL * DINNER;

        // fused per-layer prep (weight splits + padding + dt pad zero [+ x split at L0])
        if (L == 0) {
            prep_kernel<1><<<(N_PREP + N_XSPL) / 256, 256, 0, stream>>>(
                ipw_l, opw_l, xpw_l, dpw_l, x,
                wih, wil, woh, wol, wxh, wxl, wdh, wdl, dth, dtl, ah, al);
        } else {
            prep_kernel<0><<<N_PREP / 256, 256, 0, stream>>>(
                ipw_l, opw_l, xpw_l, dpw_l, x,
                wih, wil, woh, wol, wxh, wxl, wdh, wdl, dth, dtl, ah, al);
        }

        // GEMM1: xz[2048,3072] = A @ ipw^T   (pre-split bf16, MFMA)
        gemm_pre<128, 128, 0><<<dim3(2 * DINNER / 128, MTOK / 128, 1), 256, 0, stream>>>(
            ah, al, DMODEL, wih, wil, DMODEL, xz, 2 * DINNER, DMODEL, 0, 1 << 30, nullptr);

        // conv + silu -> u (bf16 hi/lo)
        conv_silu_kernel<<<(MTOK * DINNER) / 256, 256, 0, stream>>>(xz, cw_l, cb_l, uh, ul);

        // GEMM2 (split-K=16 partials): part[z][2048,80] = u-slice @ xpw-slice^T
        gemm_pre<128, NPAD, 0><<<dim3(1, MTOK / 128, KS2), 256, 0, stream>>>(
            uh, ul, DINNER, wxh, wxl, DINNER, part, XDIM,
            DINNER / KS2, (size_t)MTOK * XDIM, XDIM, nullptr);
        reduce16<<<(MTOK * XDIM / 4 + 255) / 256, 256, 0, stream>>>(part, xdbl, dth, dtl);

        // GEMM3: delta = softplus(dt @ dpw^T + dpb)   (K padded to 64)
        gemm_pre<128, 128, 2><<<dim3(DINNER / 128, MTOK / 128, 1), 256, 0, stream>>>(
            dth, dtl, KPAD, wdh, wdl, KPAD, delta, DINNER, KPAD, 0, 1 << 30, dpb_l);

        // chunked scan; pass3 emits y as bf16 hi/lo
        scan_pass1<<<(BATCH * NCHUNK * DINNER) / 256, 256, 0, stream>>>(
            delta, uh, ul, xdbl, alog_l, pbuf, qbuf);
        scan_pass2<<<CHSTRIDE / 256, 256, 0, stream>>>(pbuf, qbuf, hinit);
        scan_pass3<<<(BATCH * NCHUNK * DINNER) / 256, 256, 0, stream>>>(
            delta, uh, ul, xdbl, xz, alog_l, dpar_l, hinit, yh, yl);

        // GEMM4 (split-K=4): part[z][2048,768] = y @ opw^T
        gemm_pre<128, 128, 0><<<dim3(DMODEL / 128, MTOK / 128, 4), 256, 0, stream>>>(
            yh, yl, DINNER, woh, wol, DINNER, part, DMODEL,
            DINNER / 4, (size_t)MTOK * DMODEL, 1 << 30, nullptr);

        // reduce split-K; L<3 -> next layer's A (bf16 hi/lo), L==3 -> fp32 out
        int rblocks = MTOK * DMODEL / 4 / 256;
        if (L == NL - 1) {
            reduce4<0><<<rblocks, 256, 0, stream>>>(part, out, nullptr, nullptr);
        } else {
            reduce4<1><<<rblocks, 256, 0, stream>>>(part, nullptr, ah, al);
        }
    }
    (void)in_sizes; (void)n_in; (void)out_size; (void)ws_size;
}